// Round 7
// baseline (703.754 us; speedup 1.0000x reference)
//
#include <hip/hip_runtime.h>
#include <hip/hip_bf16.h>

// Problem constants (fixed by setup_inputs)
#define B_    16
#define N1    1024
#define NP    4096
#define D1c   256
#define D2c   128
#define DH    256
#define NQ    (B_*NP)        // 65536 rows
#define KD1   (D1c+D2c)      // 384

// Workspace layout (bytes).
#define X_OFF      0ul                     // x bf16: 65536*384*2
#define Y1_OFF     50331648ul              // y1 / y2 bf16: 65536*256*2
#define SCALE1_OFF 85458944ul
#define SHIFT1_OFF (SCALE1_OFF+1024ul)
#define SCALE2_OFF (SCALE1_OFF+2048ul)
#define SHIFT2_OFF (SCALE1_OFF+3072ul)
#define CNT_OFF    (SCALE1_OFF+4096ul)     // 2 ints: done-counters for gemm1/2
#define W1B_OFF    85467136ul              // bf16 W1: 256*384*2
#define W2B_OFF    85663744ul              // bf16 W2: 256*256*2
#define PS_OFF     85794816ul              // float Psum[1024][256] = 1 MB
#define PQ_OFF     86843392ul              // float Psq [1024][256] = 1 MB

using short8  = __attribute__((ext_vector_type(8))) short;
using floatx4 = __attribute__((ext_vector_type(4))) float;
using f4v     = __attribute__((ext_vector_type(4))) float;
using f2v     = __attribute__((ext_vector_type(2))) float;
typedef const __attribute__((address_space(1))) unsigned int* gas_t;
typedef __attribute__((address_space(3))) unsigned int* las_t;
typedef const __attribute__((address_space(4))) float* c4f_t;   // constant AS -> s_load
typedef const __attribute__((address_space(4))) f4v*   c4v_t;

// bf16 RNE cast (bit-level, matches np/jax round-to-nearest-even; inputs finite)
static __device__ __forceinline__ unsigned short f2b(float f) {
    unsigned int u = __builtin_bit_cast(unsigned int, f);
    return (unsigned short)((u + 0x7FFFu + ((u >> 16) & 1u)) >> 16);
}
static __device__ __forceinline__ float b2f(unsigned short u) {
    unsigned int x = ((unsigned int)u) << 16;
    return __builtin_bit_cast(float, x);
}

// ---------------- fused kNN + interp/concat (+ weight cvt on spare blocks) ----
// R11-proven structure, unchanged except: first weight-cvt block also zeroes
// the two gemm done-counters (runs strictly before gemm1 in stream order, so
// counters are re-initialized every iteration even if workspace is poisoned).
__global__ __launch_bounds__(512, 8) void knn_interp_kernel(
    const float* __restrict__ xyz1, const float* __restrict__ xyz2,
    const float* __restrict__ f1,   const float* __restrict__ feat2,
    const float* __restrict__ W1,   const float* __restrict__ W2,
    unsigned short* __restrict__ W1b, unsigned short* __restrict__ W2b,
    unsigned short* __restrict__ x,  int* __restrict__ cnt)
{
#pragma clang fp contract(off)
    const int tid = threadIdx.x;
    if (blockIdx.x >= 1024) {            // ---- weight conversion blocks ----
        if (blockIdx.x == 1024 && tid < 2) cnt[tid] = 0;   // reset done-counters
        int i = (blockIdx.x - 1024) * 512 + tid;     // 320 blocks x 512 = 163840
        if (i < DH * KD1) W1b[i] = f2b(W1[i]);
        else              W2b[i - DH * KD1] = f2b(W2[i - DH * KD1]);
        return;
    }

    __shared__ float pd[24 * 64];
    __shared__ int   pi[24 * 64];
    __shared__ int   sidx[64 * 3];
    __shared__ float swt [64 * 3];

    const int xcd  = blockIdx.x & 7;
    const int slot = blockIdx.x >> 3;          // 0..127
    const int batch = xcd * 2 + (slot >> 6);
    const int qblk  = slot & 63;

    const int ql  = tid & 63;
    const int seg = tid >> 6;                  // 0..7, wave index (uniform)
    const int seg_u = __builtin_amdgcn_readfirstlane(seg);
    const int n = batch * NP + qblk * 64 + ql;
    const float* qp = xyz2 + (size_t)n * 3;
    const float qx = qp[0], qy = qp[1], qz = qp[2];
    const f2v qx2 = {qx, qx}, qy2 = {qy, qy}, qz2 = {qz, qz};

    c4f_t cp = (c4f_t)(const void*)(xyz1 + (size_t)batch * (N1 * 3))
               + (size_t)seg_u * 384;          // 128 candidates * 3 floats

    float d0 = 3.4e38f, d1v = 3.4e38f, d2v = 3.4e38f;
    int   i0 = 0, i1 = 0, i2 = 0;

#define SEL(jj, dd) do {                                                      \
        bool c0 = (dd) < d0, c1 = (dd) < d1v, c2 = (dd) < d2v;                \
        i2 = c2 ? (c1 ? i1 : (jj)) : i2;                                      \
        i1 = c1 ? (c0 ? i0 : (jj)) : i1;                                      \
        i0 = c0 ? (jj) : i0;                                                  \
        d2v = __builtin_amdgcn_fmed3f(d1v, d2v, (dd));                        \
        d1v = __builtin_amdgcn_fmed3f(d0, d1v, (dd));                        \
        d0  = fminf(d0, (dd));                                                \
    } while (0)

    const int jbase = seg_u * 128;
    // explicit next-iteration prefetch rotation of the candidate triple
    f4v p0 = *(c4v_t)(cp);
    f4v p1 = *(c4v_t)(cp + 4);
    f4v p2 = *(c4v_t)(cp + 8);
    for (int j = 0; j < 128; j += 4) {
        f4v q0 = p0, q1 = p1, q2 = p2;
        if (j + 4 < 128) {
            p0 = *(c4v_t)(cp + (j + 4) * 3);
            p1 = *(c4v_t)(cp + (j + 4) * 3 + 4);
            p2 = *(c4v_t)(cp + (j + 4) * 3 + 8);
        }
        {
            f2v cx2 = {q0.x, q0.w}, cy2 = {q0.y, q1.x}, cz2 = {q0.z, q1.y};
            f2v dx2 = qx2 - cx2, dy2 = qy2 - cy2, dz2 = qz2 - cz2;
            f2v dd2 = (dx2 * dx2 + dy2 * dy2) + dz2 * dz2;
            SEL(jbase + j + 0, dd2.x);
            SEL(jbase + j + 1, dd2.y);
        }
        {
            f2v cx2 = {q1.z, q2.y}, cy2 = {q1.w, q2.z}, cz2 = {q2.x, q2.w};
            f2v dx2 = qx2 - cx2, dy2 = qy2 - cy2, dz2 = qz2 - cz2;
            f2v dd2 = (dx2 * dx2 + dy2 * dy2) + dz2 * dz2;
            SEL(jbase + j + 2, dd2.x);
            SEL(jbase + j + 3, dd2.y);
        }
    }
#undef SEL

    pd[(seg * 3 + 0) * 64 + ql] = d0;   pi[(seg * 3 + 0) * 64 + ql] = i0;
    pd[(seg * 3 + 1) * 64 + ql] = d1v;  pi[(seg * 3 + 1) * 64 + ql] = i1;
    pd[(seg * 3 + 2) * 64 + ql] = d2v;  pi[(seg * 3 + 2) * 64 + ql] = i2;
    __syncthreads();

    if (tid < 64) {
        float e0 = pd[0 * 64 + tid], e1 = pd[1 * 64 + tid], e2 = pd[2 * 64 + tid];
        int   j0 = pi[0 * 64 + tid], j1 = pi[1 * 64 + tid], j2 = pi[2 * 64 + tid];
#pragma unroll
        for (int s = 3; s < 24; s++) {
            float d = pd[s * 64 + tid];
            int   i = pi[s * 64 + tid];
            bool c2 = d < e2;
            e2 = c2 ? d : e2;  j2 = c2 ? i : j2;
            bool c1 = e2 < e1;
            float tf = e1; e1 = c1 ? e2 : e1; e2 = c1 ? tf : e2;
            int   ti = j1; j1 = c1 ? j2 : j1; j2 = c1 ? ti : j2;
            bool c0 = e1 < e0;
            tf = e0; e0 = c0 ? e1 : e0; e1 = c0 ? tf : e1;
            ti = j0; j0 = c0 ? j1 : j0; j1 = c0 ? ti : j1;
        }
        const float eps = 1.1920929e-07f;
        float v0 = 1.0f / __fadd_rn(e0, eps);
        float v1 = 1.0f / __fadd_rn(e1, eps);
        float v2 = 1.0f / __fadd_rn(e2, eps);
        float s  = __fadd_rn(__fadd_rn(v0, v1), v2);
        sidx[tid * 3 + 0] = j0;  swt[tid * 3 + 0] = v0 / s;
        sidx[tid * 3 + 1] = j1;  swt[tid * 3 + 1] = v1 / s;
        sidx[tid * 3 + 2] = j2;  swt[tid * 3 + 2] = v2 / s;
    }
    __syncthreads();

    const int lane = tid & 63, wv = tid >> 6;
    const float* fb = f1 + (size_t)batch * (N1 * D1c);
#pragma unroll 4
    for (int it = 0; it < 8; it++) {
        const int q  = wv * 8 + it;
        const int nr = batch * NP + qblk * 64 + q;
        const int a0 = sidx[q * 3 + 0], a1 = sidx[q * 3 + 1], a2 = sidx[q * 3 + 2];
        const float w0 = swt[q * 3 + 0], w1 = swt[q * 3 + 1], w2 = swt[q * 3 + 2];
        float4 a = *(const float4*)(fb + (size_t)a0 * D1c + lane * 4);
        float4 b = *(const float4*)(fb + (size_t)a1 * D1c + lane * 4);
        float4 c = *(const float4*)(fb + (size_t)a2 * D1c + lane * 4);
        ushort4 o;
        o.x = f2b(__fadd_rn(__fadd_rn(__fmul_rn(a.x,w0), __fmul_rn(b.x,w1)), __fmul_rn(c.x,w2)));
        o.y = f2b(__fadd_rn(__fadd_rn(__fmul_rn(a.y,w0), __fmul_rn(b.y,w1)), __fmul_rn(c.y,w2)));
        o.z = f2b(__fadd_rn(__fadd_rn(__fmul_rn(a.z,w0), __fmul_rn(b.z,w1)), __fmul_rn(c.z,w2)));
        o.w = f2b(__fadd_rn(__fadd_rn(__fmul_rn(a.w,w0), __fmul_rn(b.w,w1)), __fmul_rn(c.w,w2)));
        *(ushort4*)(x + (size_t)nr * KD1 + lane * 4) = o;
        float2 f = *(const float2*)(feat2 + (size_t)nr * D2c + lane * 2);
        ushort2 o2; o2.x = f2b(f.x); o2.y = f2b(f.y);
        *(ushort2*)(x + (size_t)nr * KD1 + D1c + lane * 2) = o2;
    }
}

// ---------------- shared gemm epilogue, BM=64 variant (R8-proven) ------------
static __device__ __forceinline__ void gemm_epilogue64(
    short* smem, floatx4 (&acc)[2][4], const float* __restrict__ bias,
    unsigned short* __restrict__ Out, float* __restrict__ Psum, float* __restrict__ Psq,
    long m0, int tid, int wm, int wn, int quad, int l16, int pslot)
{
    float sv[4], qv[4];
#pragma unroll
    for (int nb = 0; nb < 4; nb++) {
        const int col = wn * 64 + nb * 16 + l16;
        const float bia = bias[col];
        float s = 0.f, q = 0.f;
#pragma unroll
        for (int mb = 0; mb < 2; mb++)
#pragma unroll
            for (int r = 0; r < 4; r++) {
                float v = acc[mb][nb][r] + bia;
                acc[mb][nb][r] = v;
                s += v; q += v * v;
            }
        s += __shfl_xor(s, 16); s += __shfl_xor(s, 32);
        q += __shfl_xor(q, 16); q += __shfl_xor(q, 32);
        sv[nb] = s; qv[nb] = q;
    }
    // combine wm halves via LDS floats (first 4 KB of smem; K-loop done)
    float* fs = (float*)smem;          // 512 floats: [wm][col]
    float* fq = (float*)smem + 512;    // 512 floats
    if (quad == 0) {
#pragma unroll
        for (int nb = 0; nb < 4; nb++) {
            const int col = wn * 64 + nb * 16 + l16;
            fs[wm * 256 + col] = sv[nb];
            fq[wm * 256 + col] = qv[nb];
        }
    }
    __syncthreads();
    if (wm == 0 && quad == 0) {
#pragma unroll
        for (int nb = 0; nb < 4; nb++) {
            const int col = wn * 64 + nb * 16 + l16;
            Psum[pslot * 256 + col] = fs[col] + fs[256 + col];
            Psq [pslot * 256 + col] = fq[col] + fq[256 + col];
        }
    }
    __syncthreads();   // fs/fq reads done before transpose overwrites region

#pragma unroll
    for (int mb = 0; mb < 2; mb++)
#pragma unroll
        for (int r = 0; r < 4; r++) {
            const int rl = wm * 32 + mb * 16 + quad * 4 + r;
#pragma unroll
            for (int nb = 0; nb < 4; nb++) {
                const int col = wn * 64 + nb * 16 + l16;
                smem[rl * 256 + ((((col >> 3) + rl) & 31) << 3) + (col & 7)] =
                    (short)f2b(acc[mb][nb][r]);
            }
        }
    __syncthreads();
#pragma unroll
    for (int rr = 0; rr < 4; rr++) {
        const int rl = rr * 16 + (tid >> 5);
        const int c  = tid & 31;
        short8 v = *(const short8*)(smem + rl * 256 + (((c + rl) & 31) << 3));
        *(short8*)(Out + (size_t)(m0 + rl) * 256 + c * 8) = v;
    }
}

// ---------------- fused BN finalize tail (R13) -------------------------------
// Every block: fence + done-counter bump. Blocks 960..1023 (launched last ->
// minimal spin) wait for all 1024, then run the R11-proven finalize for their
// 4 columns. Structurally deadlock-free: only 64 of 1024 blocks ever spin.
static __device__ __forceinline__ void fused_finalize(
    short* smem, int tid, int bx, int* __restrict__ cnt,
    const float* __restrict__ Psum, const float* __restrict__ Psq,
    const float* __restrict__ g, const float* __restrict__ beta,
    float* __restrict__ scale, float* __restrict__ shift)
{
    __threadfence();                 // each thread's Psum/Psq stores -> device
    __syncthreads();                 // all threads fenced before the bump
    if (tid == 0)
        __hip_atomic_fetch_add(cnt, 1, __ATOMIC_ACQ_REL, __HIP_MEMORY_SCOPE_AGENT);
    if (bx >= 960) {
        if (tid == 0)
            while (__hip_atomic_load(cnt, __ATOMIC_ACQUIRE, __HIP_MEMORY_SCOPE_AGENT) < 1024)
                __builtin_amdgcn_s_sleep(2);
        __syncthreads();             // stats now globally visible
        float* ls = (float*)smem;        // [4][4]
        float* lq = (float*)smem + 16;   // [4][4]
        const int c4 = tid & 3;
        const int col = (bx - 960) * 4 + c4;
        if (tid < 256) {
            const int r = tid >> 2;      // 0..63
            float s = 0.f, q = 0.f;
#pragma unroll
            for (int i = 0; i < 16; i++) {
                const int k = r + i * 64;
                s += Psum[k * 256 + col];
                q += Psq [k * 256 + col];
            }
            s += __shfl_xor(s, 4);  q += __shfl_xor(q, 4);
            s += __shfl_xor(s, 8);  q += __shfl_xor(q, 8);
            s += __shfl_xor(s, 16); q += __shfl_xor(q, 16);
            s += __shfl_xor(s, 32); q += __shfl_xor(q, 32);
            const int wv = tid >> 6;
            if ((tid & 63) < 4) { ls[wv * 4 + c4] = s; lq[wv * 4 + c4] = q; }
        }
        __syncthreads();
        if (tid < 4) {
            float s = ls[0 * 4 + tid] + ls[1 * 4 + tid] + ls[2 * 4 + tid] + ls[3 * 4 + tid];
            float q = lq[0 * 4 + tid] + lq[1 * 4 + tid] + lq[2 * 4 + tid] + lq[3 * 4 + tid];
            const int c = (bx - 960) * 4 + tid;
            float m  = s * (1.0f / (float)NQ);
            float v  = q * (1.0f / (float)NQ) - m * m;
            float rs = rsqrtf(v + 1e-5f);
            float a  = rs * g[c];
            scale[c] = a;
            shift[c] = fmaf(-m, a, beta[c]);
        }
    }
}

// ---------------- gemm1: y1 = X @ W1b^T + b1, stats fused, BM=64 (R8) --------
__global__ __launch_bounds__(512, 6) void gemm_bn1(
    const unsigned short* __restrict__ A,
    const unsigned short* __restrict__ Bw,
    const float* __restrict__ bias,
    unsigned short* __restrict__ Out,
    float* __restrict__ Psum, float* __restrict__ Psq,
    const float* __restrict__ g, const float* __restrict__ beta,
    float* __restrict__ scale, float* __restrict__ shift,
    int* __restrict__ cnt)
{
    __shared__ short smem[20480];   // 40 KB: As[2] @ 0/2048, Bs[2] @ 4096/12288
    const int tid  = threadIdx.x;
    const int wave = tid >> 6, lane = tid & 63;
    const int wm   = wave & 1, wn = wave >> 1;
    const int quad = lane >> 4, l16 = lane & 15;
    const long m0 = (long)blockIdx.x * 64;

    const int srow = tid >> 2;                              // 0..127
    const int cg   = ((tid & 3) ^ ((tid >> 3) & 3)) * 8;
    const size_t aoff  = (size_t)(m0 + (srow & 63)) * KD1 + cg;  // used by tid<256
    const size_t boff0 = (size_t)(srow) * KD1 + cg;
    const size_t boff1 = (size_t)(128 + srow) * KD1 + cg;

    floatx4 acc[2][4];
#pragma unroll
    for (int a = 0; a < 2; a++)
#pragma unroll
        for (int b = 0; b < 4; b++)
            acc[a][b] = floatx4{0.f, 0.f, 0.f, 0.f};

    const int rsw = (l16 >> 1) & 3;

#define STAGE(buf, ck) do {                                                         \
        if (tid < 256)                                                              \
        __builtin_amdgcn_global_load_lds((gas_t)(const void*)(A + aoff + (ck)*32),  \
            (las_t)(void*)(smem + (buf)*2048 + wave*512), 16, 0, 0);                \
        __builtin_amdgcn_global_load_lds((gas_t)(const void*)(Bw + boff0 + (ck)*32),\
            (las_t)(void*)(smem + 4096 + (buf)*8192 + wave*512), 16, 0, 0);         \
        __builtin_amdgcn_global_load_lds((gas_t)(const void*)(Bw + boff1 + (ck)*32),\
            (las_t)(void*)(smem + 4096 + (buf)*8192 + 4096 + wave*512), 16, 0, 0);  \
    } while (0)

    STAGE(0, 0);
    __syncthreads();
    for (int ck = 0; ck < 12; ck++) {
        const int cur = ck & 1;
        if (ck + 1 < 12) STAGE(cur ^ 1, ck + 1);
        const short* Ab = smem + cur * 2048;
        const short* Bb = smem + 4096 + cur * 8192;
        short8 af[2], bfr[4];
#pragma unroll
        for (int mb = 0; mb < 2; mb++)
            af[mb] = *(const short8*)(Ab + (wm * 32 + mb * 16 + l16) * 32 + ((quad ^ rsw) * 8));
#pragma unroll
        for (int nb = 0; nb < 4; nb++)
            bfr[nb] = *(const short8*)(Bb + (wn * 64 + nb * 16 + l16) * 32 + ((quad ^ rsw) * 8));
#pragma unroll
        for (int mb = 0; mb < 2; mb++)
#pragma unroll
            for (int nb = 0; nb < 4; nb++)
                acc[mb][nb] = __builtin_amdgcn_mfma_f32_16x16x32_bf16(af[mb], bfr[nb], acc[mb][nb], 0, 0, 0);
        __syncthreads();
    }
#undef STAGE

    gemm_epilogue64(smem, acc, bias, Out, Psum, Psq, m0, tid, wm, wn, quad, l16,
                    blockIdx.x);
    fused_finalize(smem, tid, blockIdx.x, cnt, Psum, Psq, g, beta, scale, shift);
}

// ---------------- gemm2: y2 = relu(BN1(y1)) @ W2b^T + b2, BN1 fused (R8) -----
__global__ __launch_bounds__(512, 6) void gemm_bn2(
    const unsigned short* __restrict__ Y1in,
    const unsigned short* __restrict__ W2b,
    const float* __restrict__ SC1, const float* __restrict__ SH1,
    const float* __restrict__ b2,
    unsigned short* __restrict__ Y2out,
    float* __restrict__ Psum, float* __restrict__ Psq,
    const float* __restrict__ g, const float* __restrict__ beta,
    float* __restrict__ scale, float* __restrict__ shift,
    int* __restrict__ cnt)
{
    __shared__ short smem[20480];   // 40 KB: As[2] @ 0/2048, Bs[2] @ 4096/12288
    const int tid  = threadIdx.x;
    const int wave = tid >> 6, lane = tid & 63;
    const int wm   = wave & 1, wn = wave >> 1;
    const int quad = lane >> 4, l16 = lane & 15;
    const long m0 = (long)blockIdx.x * 64;

    const int srow = tid >> 2;                              // 0..127
    const int cg   = ((tid & 3) ^ ((tid >> 3) & 3)) * 8;    // source col-chunk base
    const unsigned short* Ap = Y1in + (size_t)(m0 + (srow & 63)) * 256 + cg;
    const size_t boff0 = (size_t)(srow) * 256 + cg;
    const size_t boff1 = (size_t)(128 + srow) * 256 + cg;

    floatx4 acc[2][4];
#pragma unroll
    for (int a = 0; a < 2; a++)
#pragma unroll
        for (int b = 0; b < 4; b++)
            acc[a][b] = floatx4{0.f, 0.f, 0.f, 0.f};

    const int rsw = (l16 >> 1) & 3;

#define STAGE_B(buf, ck) do {                                                        \
        __builtin_amdgcn_global_load_lds((gas_t)(const void*)(W2b + boff0 + (ck)*32),\
            (las_t)(void*)(smem + 4096 + (buf)*8192 + wave*512), 16, 0, 0);          \
        __builtin_amdgcn_global_load_lds((gas_t)(const void*)(W2b + boff1 + (ck)*32),\
            (las_t)(void*)(smem + 4096 + (buf)*8192 + 4096 + wave*512), 16, 0, 0);   \
    } while (0)

    // transform-write of A chunk ck into buffer buf (tid<256 only; regs preloaded)
#define XSTORE(buf, ck, r0, r1) do {                                            \
        const int c0 = (ck) * 32 + cg;                                          \
        float4 s0 = *(const float4*)(SC1 + c0), s1 = *(const float4*)(SC1 + c0 + 4); \
        float4 h0 = *(const float4*)(SH1 + c0), h1 = *(const float4*)(SH1 + c0 + 4); \
        short8 o;                                                               \
        o[0] = (short)f2b(fmaxf(fmaf(b2f(r0.x), s0.x, h0.x), 0.f));             \
        o[1] = (short)f2b(fmaxf(fmaf(b2f(r0.y), s0.y, h0.y), 0.f));             \
        o[2] = (short)f2b(fmaxf(fmaf(b2f(r0.z), s0.z, h0.z), 0.f));             \
        o[3] = (short)f2b(fmaxf(fmaf(b2f(r0.w), s0.w, h0.w), 0.f));             \
        o[4] = (short)f2b(fmaxf(fmaf(b2f(r1.x), s1.x, h1.x), 0.f));             \
        o[5] = (short)f2b(fmaxf(fmaf(b2f(r1.y), s1.y, h1.y), 0.f));             \
        o[6] = (short)f2b(fmaxf(fmaf(b2f(r1.z), s1.z, h1.z), 0.f));             \
        o[7] = (short)f2b(fmaxf(fmaf(b2f(r1.w), s1.w, h1.w), 0.f));             \
        *(short8*)(smem + (buf) * 2048 + tid * 8) = o;                          \
    } while (0)

    if (tid < 256) {
        ushort4 r0 = *(const ushort4*)(Ap);
        ushort4 r1 = *(const ushort4*)(Ap + 4);
        XSTORE(0, 0, r0, r1);
    }
    STAGE_B(0, 0);
    __syncthreads();
    for (int ck = 0; ck < 8; ck++) {
        const int cur = ck & 1;
        ushort4 r0 = {}, r1 = {};
        if (tid < 256 && ck + 1 < 8) {          // issue next-A loads early
            r0 = *(const ushort4*)(Ap + (ck + 1) * 32);
            r1 = *(const ushort4*)(Ap + (ck + 1) * 32 + 4);
        }
        if (ck + 1 < 8) STAGE_B(cur ^ 1, ck + 1);
        const short* Ab = smem + cur * 2048;
        const short* Bb = smem + 4096 + cur * 8192;
        short8 af[2], bfr[4];
#pragma unroll
        for (int mb = 0; mb < 2; mb++)
            af[mb] = *(const short8*)(Ab + (wm * 32 + mb * 16 + l16) * 32 + ((quad ^ rsw) * 8));
#pragma unroll
        for (int nb = 0; nb < 4; nb++)
            bfr[nb] = *(const short8*)(Bb + (wn * 64 + nb * 16 + l16) * 32 + ((quad ^ rsw) * 8));
#pragma unroll
        for (int mb = 0; mb < 2; mb++)
#pragma unroll
            for (int nb = 0; nb < 4; nb++)
                acc[mb][nb] = __builtin_amdgcn_mfma_f32_16x16x32_bf16(af[mb], bfr[nb], acc[mb][nb], 0, 0, 0);
        if (tid < 256 && ck + 1 < 8) XSTORE(cur ^ 1, ck + 1, r0, r1);  // after MFMAs
        __syncthreads();
    }
#undef XSTORE
#undef STAGE_B

    gemm_epilogue64(smem, acc, b2, Y2out, Psum, Psq, m0, tid, wm, wn, quad, l16,
                    blockIdx.x);
    fused_finalize(smem, tid, blockIdx.x, cnt, Psum, Psq, g, beta, scale, shift);
}

// ---------------- final BN apply + relu: y2 bf16 -> d_out fp32 ----------------
__global__ __launch_bounds__(256) void final_apply(
    const unsigned short* __restrict__ y2, const float* __restrict__ scale,
    const float* __restrict__ shift, float* __restrict__ out)
{
    size_t t = (size_t)blockIdx.x * 256 + threadIdx.x;   // 2,097,152 threads x 8 elems
    int c = ((int)t & 31) * 8;
    const ushort4* in = (const ushort4*)y2 + t * 2;
    ushort4 a = in[0], b = in[1];
    float4 s0 = *(const float4*)(scale + c), s1 = *(const float4*)(scale + c + 4);
    float4 h0 = *(const float4*)(shift + c), h1 = *(const float4*)(shift + c + 4);
    float4 o0, o1;
    o0.x = fmaxf(fmaf(b2f(a.x), s0.x, h0.x), 0.f);
    o0.y = fmaxf(fmaf(b2f(a.y), s0.y, h0.y), 0.f);
    o0.z = fmaxf(fmaf(b2f(a.z), s0.z, h0.z), 0.f);
    o0.w = fmaxf(fmaf(b2f(a.w), s0.w, h0.w), 0.f);
    o1.x = fmaxf(fmaf(b2f(b.x), s1.x, h1.x), 0.f);
    o1.y = fmaxf(fmaf(b2f(b.y), s1.y, h1.y), 0.f);
    o1.z = fmaxf(fmaf(b2f(b.z), s1.z, h1.z), 0.f);
    o1.w = fmaxf(fmaf(b2f(b.w), s1.w, h1.w), 0.f);
    ((float4*)out)[t * 2]     = o0;
    ((float4*)out)[t * 2 + 1] = o1;
}

extern "C" void kernel_launch(void* const* d_in, const int* in_sizes, int n_in,
                              void* d_out, int out_size, void* d_ws, size_t ws_size,
                              hipStream_t stream) {
    (void)in_sizes; (void)n_in; (void)out_size; (void)ws_size;
    const float* xyz1 = (const float*)d_in[0];
    const float* xyz2 = (const float*)d_in[1];
    const float* f1   = (const float*)d_in[2];
    const float* f2   = (const float*)d_in[3];
    const float* W1   = (const float*)d_in[4];
    const float* b1   = (const float*)d_in[5];
    const float* g1   = (const float*)d_in[6];
    const float* be1  = (const float*)d_in[7];
    const float* W2   = (const float*)d_in[8];
    const float* b2   = (const float*)d_in[9];
    const float* g2   = (const float*)d_in[10];
    const float* be2  = (const float*)d_in[11];

    char* ws = (char*)d_ws;
    unsigned short* X    = (unsigned short*)(ws + X_OFF);
    unsigned short* Y1   = (unsigned short*)(ws + Y1_OFF);    // y1, reused as y2
    float*          SC1  = (float*)(ws + SCALE1_OFF);
    float*          SH1  = (float*)(ws + SHIFT1_OFF);
    float*          SC2  = (float*)(ws + SCALE2_OFF);
    float*          SH2  = (float*)(ws + SHIFT2_OFF);
    int*            CNT  = (int*)(ws + CNT_OFF);
    unsigned short* W1b  = (unsigned short*)(ws + W1B_OFF);
    unsigned short* W2b  = (unsigned short*)(ws + W2B_OFF);
    float*          PS   = (float*)(ws + PS_OFF);
    float*          PQ   = (float*)(ws + PQ_OFF);

    knn_interp_kernel<<<1344, 512, 0, stream>>>(xyz1, xyz2, f1, f2, W1, W2, W1b, W2b, X, CNT);
    gemm_bn1<<<1024, 512, 0, stream>>>(X, W1b, b1, Y1, PS, PQ, g1, be1, SC1, SH1, CNT);
    gemm_bn2<<<1024, 512, 0, stream>>>(Y1, W2b, SC1, SH1, b2, Y1, PS, PQ, g2, be2, SC2, SH2, CNT + 1);
    final_apply<<<(NQ * DH) / (8 * 256), 256, 0, stream>>>(Y1, SC2, SH2, (float*)d_out);
}

// Round 9
// 254.369 us; speedup vs baseline: 2.7667x; 2.7667x over previous
//
#include <hip/hip_runtime.h>
#include <hip/hip_bf16.h>

// Problem constants (fixed by setup_inputs)
#define B_    16
#define N1    1024
#define NP    4096
#define D1c   256
#define D2c   128
#define DH    256
#define NQ    (B_*NP)        // 65536 rows
#define KD1   (D1c+D2c)      // 384

// Workspace layout (bytes).
#define X_OFF      0ul                     // x bf16: 65536*384*2
#define Y1_OFF     50331648ul              // y1 / y2 bf16: 65536*256*2
#define W1B_OFF    85467136ul              // bf16 W1: 256*384*2
#define W2B_OFF    85663744ul              // bf16 W2: 256*256*2
#define PS_OFF     85794816ul              // BN accumulators: 4 x 256 floats
// PS1s @ +0, PS1q @ +1024, PS2s @ +2048, PS2q @ +3072 (bytes)

using short8  = __attribute__((ext_vector_type(8))) short;
using floatx4 = __attribute__((ext_vector_type(4))) float;
using f4v     = __attribute__((ext_vector_type(4))) float;
using f2v     = __attribute__((ext_vector_type(2))) float;
typedef const __attribute__((address_space(1))) unsigned int* gas_t;
typedef __attribute__((address_space(3))) unsigned int* las_t;
typedef const __attribute__((address_space(4))) float* c4f_t;   // constant AS -> s_load
typedef const __attribute__((address_space(4))) f4v*   c4v_t;

// bf16 RNE cast (bit-level, matches np/jax round-to-nearest-even; inputs finite)
static __device__ __forceinline__ unsigned short f2b(float f) {
    unsigned int u = __builtin_bit_cast(unsigned int, f);
    return (unsigned short)((u + 0x7FFFu + ((u >> 16) & 1u)) >> 16);
}
static __device__ __forceinline__ float b2f(unsigned short u) {
    unsigned int x = ((unsigned int)u) << 16;
    return __builtin_bit_cast(float, x);
}

// ---------------- fused kNN + interp/concat (+ weight cvt on spare blocks) ----
// R11-proven; block 1024 additionally zeroes the 4x256 BN accumulators
// (stream-ordered before gemm1, so they are re-initialized every iteration).
__global__ __launch_bounds__(512, 8) void knn_interp_kernel(
    const float* __restrict__ xyz1, const float* __restrict__ xyz2,
    const float* __restrict__ f1,   const float* __restrict__ feat2,
    const float* __restrict__ W1,   const float* __restrict__ W2,
    unsigned short* __restrict__ W1b, unsigned short* __restrict__ W2b,
    unsigned short* __restrict__ x,  float* __restrict__ bnz)
{
#pragma clang fp contract(off)
    const int tid = threadIdx.x;
    if (blockIdx.x >= 1024) {            // ---- weight conversion blocks ----
        if (blockIdx.x == 1024) { bnz[tid] = 0.f; bnz[tid + 512] = 0.f; }
        int i = (blockIdx.x - 1024) * 512 + tid;     // 320 blocks x 512 = 163840
        if (i < DH * KD1) W1b[i] = f2b(W1[i]);
        else              W2b[i - DH * KD1] = f2b(W2[i - DH * KD1]);
        return;
    }

    __shared__ float pd[24 * 64];
    __shared__ int   pi[24 * 64];
    __shared__ int   sidx[64 * 3];
    __shared__ float swt [64 * 3];

    const int xcd  = blockIdx.x & 7;
    const int slot = blockIdx.x >> 3;          // 0..127
    const int batch = xcd * 2 + (slot >> 6);
    const int qblk  = slot & 63;

    const int ql  = tid & 63;
    const int seg = tid >> 6;                  // 0..7, wave index (uniform)
    const int seg_u = __builtin_amdgcn_readfirstlane(seg);
    const int n = batch * NP + qblk * 64 + ql;
    const float* qp = xyz2 + (size_t)n * 3;
    const float qx = qp[0], qy = qp[1], qz = qp[2];
    const f2v qx2 = {qx, qx}, qy2 = {qy, qy}, qz2 = {qz, qz};

    c4f_t cp = (c4f_t)(const void*)(xyz1 + (size_t)batch * (N1 * 3))
               + (size_t)seg_u * 384;          // 128 candidates * 3 floats

    float d0 = 3.4e38f, d1v = 3.4e38f, d2v = 3.4e38f;
    int   i0 = 0, i1 = 0, i2 = 0;

#define SEL(jj, dd) do {                                                      \
        bool c0 = (dd) < d0, c1 = (dd) < d1v, c2 = (dd) < d2v;                \
        i2 = c2 ? (c1 ? i1 : (jj)) : i2;                                      \
        i1 = c1 ? (c0 ? i0 : (jj)) : i1;                                      \
        i0 = c0 ? (jj) : i0;                                                  \
        d2v = __builtin_amdgcn_fmed3f(d1v, d2v, (dd));                        \
        d1v = __builtin_amdgcn_fmed3f(d0, d1v, (dd));                         \
        d0  = fminf(d0, (dd));                                                \
    } while (0)

    const int jbase = seg_u * 128;
    // explicit next-iteration prefetch rotation of the candidate triple
    f4v p0 = *(c4v_t)(cp);
    f4v p1 = *(c4v_t)(cp + 4);
    f4v p2 = *(c4v_t)(cp + 8);
    for (int j = 0; j < 128; j += 4) {
        f4v q0 = p0, q1 = p1, q2 = p2;
        if (j + 4 < 128) {
            p0 = *(c4v_t)(cp + (j + 4) * 3);
            p1 = *(c4v_t)(cp + (j + 4) * 3 + 4);
            p2 = *(c4v_t)(cp + (j + 4) * 3 + 8);
        }
        {
            f2v cx2 = {q0.x, q0.w}, cy2 = {q0.y, q1.x}, cz2 = {q0.z, q1.y};
            f2v dx2 = qx2 - cx2, dy2 = qy2 - cy2, dz2 = qz2 - cz2;
            f2v dd2 = (dx2 * dx2 + dy2 * dy2) + dz2 * dz2;
            SEL(jbase + j + 0, dd2.x);
            SEL(jbase + j + 1, dd2.y);
        }
        {
            f2v cx2 = {q1.z, q2.y}, cy2 = {q1.w, q2.z}, cz2 = {q2.x, q2.w};
            f2v dx2 = qx2 - cx2, dy2 = qy2 - cy2, dz2 = qz2 - cz2;
            f2v dd2 = (dx2 * dx2 + dy2 * dy2) + dz2 * dz2;
            SEL(jbase + j + 2, dd2.x);
            SEL(jbase + j + 3, dd2.y);
        }
    }
#undef SEL

    pd[(seg * 3 + 0) * 64 + ql] = d0;   pi[(seg * 3 + 0) * 64 + ql] = i0;
    pd[(seg * 3 + 1) * 64 + ql] = d1v;  pi[(seg * 3 + 1) * 64 + ql] = i1;
    pd[(seg * 3 + 2) * 64 + ql] = d2v;  pi[(seg * 3 + 2) * 64 + ql] = i2;
    __syncthreads();

    if (tid < 64) {
        float e0 = pd[0 * 64 + tid], e1 = pd[1 * 64 + tid], e2 = pd[2 * 64 + tid];
        int   j0 = pi[0 * 64 + tid], j1 = pi[1 * 64 + tid], j2 = pi[2 * 64 + tid];
#pragma unroll
        for (int s = 3; s < 24; s++) {
            float d = pd[s * 64 + tid];
            int   i = pi[s * 64 + tid];
            bool c2 = d < e2;
            e2 = c2 ? d : e2;  j2 = c2 ? i : j2;
            bool c1 = e2 < e1;
            float tf = e1; e1 = c1 ? e2 : e1; e2 = c1 ? tf : e2;
            int   ti = j1; j1 = c1 ? j2 : j1; j2 = c1 ? ti : j2;
            bool c0 = e1 < e0;
            tf = e0; e0 = c0 ? e1 : e0; e1 = c0 ? tf : e1;
            ti = j0; j0 = c0 ? j1 : j0; j1 = c0 ? ti : j1;
        }
        const float eps = 1.1920929e-07f;
        float v0 = 1.0f / __fadd_rn(e0, eps);
        float v1 = 1.0f / __fadd_rn(e1, eps);
        float v2 = 1.0f / __fadd_rn(e2, eps);
        float s  = __fadd_rn(__fadd_rn(v0, v1), v2);
        sidx[tid * 3 + 0] = j0;  swt[tid * 3 + 0] = v0 / s;
        sidx[tid * 3 + 1] = j1;  swt[tid * 3 + 1] = v1 / s;
        sidx[tid * 3 + 2] = j2;  swt[tid * 3 + 2] = v2 / s;
    }
    __syncthreads();

    const int lane = tid & 63, wv = tid >> 6;
    const float* fb = f1 + (size_t)batch * (N1 * D1c);
#pragma unroll 4
    for (int it = 0; it < 8; it++) {
        const int q  = wv * 8 + it;
        const int nr = batch * NP + qblk * 64 + q;
        const int a0 = sidx[q * 3 + 0], a1 = sidx[q * 3 + 1], a2 = sidx[q * 3 + 2];
        const float w0 = swt[q * 3 + 0], w1 = swt[q * 3 + 1], w2 = swt[q * 3 + 2];
        float4 a = *(const float4*)(fb + (size_t)a0 * D1c + lane * 4);
        float4 b = *(const float4*)(fb + (size_t)a1 * D1c + lane * 4);
        float4 c = *(const float4*)(fb + (size_t)a2 * D1c + lane * 4);
        ushort4 o;
        o.x = f2b(__fadd_rn(__fadd_rn(__fmul_rn(a.x,w0), __fmul_rn(b.x,w1)), __fmul_rn(c.x,w2)));
        o.y = f2b(__fadd_rn(__fadd_rn(__fmul_rn(a.y,w0), __fmul_rn(b.y,w1)), __fmul_rn(c.y,w2)));
        o.z = f2b(__fadd_rn(__fadd_rn(__fmul_rn(a.z,w0), __fmul_rn(b.z,w1)), __fmul_rn(c.z,w2)));
        o.w = f2b(__fadd_rn(__fadd_rn(__fmul_rn(a.w,w0), __fmul_rn(b.w,w1)), __fmul_rn(c.w,w2)));
        *(ushort4*)(x + (size_t)nr * KD1 + lane * 4) = o;
        float2 f = *(const float2*)(feat2 + (size_t)nr * D2c + lane * 2);
        ushort2 o2; o2.x = f2b(f.x); o2.y = f2b(f.y);
        *(ushort2*)(x + (size_t)nr * KD1 + D1c + lane * 2) = o2;
    }
}

// ---------------- shared gemm epilogue, BM=64 (R8-proven) --------------------
// R15: per-tile column sums (bit-identical to R11) now atomicAdd into global
// [256] accumulators instead of a per-tile Psum row. Cross-tile order becomes
// atomic-ordered (<=1 bf16 ULP effect on final outputs).
static __device__ __forceinline__ void gemm_epilogue64(
    short* smem, floatx4 (&acc)[2][4], const float* __restrict__ bias,
    unsigned short* __restrict__ Out, float* __restrict__ Ss, float* __restrict__ Sq,
    long m0, int tid, int wm, int wn, int quad, int l16)
{
    float sv[4], qv[4];
#pragma unroll
    for (int nb = 0; nb < 4; nb++) {
        const int col = wn * 64 + nb * 16 + l16;
        const float bia = bias[col];
        float s = 0.f, q = 0.f;
#pragma unroll
        for (int mb = 0; mb < 2; mb++)
#pragma unroll
            for (int r = 0; r < 4; r++) {
                float v = acc[mb][nb][r] + bia;
                acc[mb][nb][r] = v;
                s += v; q += v * v;
            }
        s += __shfl_xor(s, 16); s += __shfl_xor(s, 32);
        q += __shfl_xor(q, 16); q += __shfl_xor(q, 32);
        sv[nb] = s; qv[nb] = q;
    }
    // combine wm halves via LDS floats (first 4 KB of smem; K-loop done)
    float* fs = (float*)smem;          // 512 floats: [wm][col]
    float* fq = (float*)smem + 512;    // 512 floats
    if (quad == 0) {
#pragma unroll
        for (int nb = 0; nb < 4; nb++) {
            const int col = wn * 64 + nb * 16 + l16;
            fs[wm * 256 + col] = sv[nb];
            fq[wm * 256 + col] = qv[nb];
        }
    }
    __syncthreads();
    if (wm == 0 && quad == 0) {
#pragma unroll
        for (int nb = 0; nb < 4; nb++) {
            const int col = wn * 64 + nb * 16 + l16;
            atomicAdd(&Ss[col], fs[col] + fs[256 + col]);
            atomicAdd(&Sq[col], fq[col] + fq[256 + col]);
        }
    }
    __syncthreads();   // fs/fq reads done before transpose overwrites region

#pragma unroll
    for (int mb = 0; mb < 2; mb++)
#pragma unroll
        for (int r = 0; r < 4; r++) {
            const int rl = wm * 32 + mb * 16 + quad * 4 + r;
#pragma unroll
            for (int nb = 0; nb < 4; nb++) {
                const int col = wn * 64 + nb * 16 + l16;
                smem[rl * 256 + ((((col >> 3) + rl) & 31) << 3) + (col & 7)] =
                    (short)f2b(acc[mb][nb][r]);
            }
        }
    __syncthreads();
#pragma unroll
    for (int rr = 0; rr < 4; rr++) {
        const int rl = rr * 16 + (tid >> 5);
        const int c  = tid & 31;
        short8 v = *(const short8*)(smem + rl * 256 + (((c + rl) & 31) << 3));
        *(short8*)(Out + (size_t)(m0 + rl) * 256 + c * 8) = v;
    }
}

// BN scale/shift from accumulated sums (exact finalize_bn arithmetic)
static __device__ __forceinline__ void bn_scale_shift(
    float s, float q, float gg, float bb, float& sc, float& sh)
{
    float m  = s * (1.0f / (float)NQ);
    float v  = q * (1.0f / (float)NQ) - m * m;
    float rs = rsqrtf(v + 1e-5f);
    float a  = rs * gg;
    sc = a;
    sh = fmaf(-m, a, bb);
}

// ---------------- gemm1: y1 = X @ W1b^T + b1, stats -> atomics (R11 body) ----
__global__ __launch_bounds__(512, 6) void gemm_bn1(
    const unsigned short* __restrict__ A,
    const unsigned short* __restrict__ Bw,
    const float* __restrict__ bias,
    unsigned short* __restrict__ Out,
    float* __restrict__ Ss, float* __restrict__ Sq)
{
    __shared__ short smem[20480];   // 40 KB: As[2] @ 0/2048, Bs[2] @ 4096/12288
    const int tid  = threadIdx.x;
    const int wave = tid >> 6, lane = tid & 63;
    const int wm   = wave & 1, wn = wave >> 1;
    const int quad = lane >> 4, l16 = lane & 15;
    const long m0 = (long)blockIdx.x * 64;

    const int srow = tid >> 2;                              // 0..127
    const int cg   = ((tid & 3) ^ ((tid >> 3) & 3)) * 8;
    const size_t aoff  = (size_t)(m0 + (srow & 63)) * KD1 + cg;  // used by tid<256
    const size_t boff0 = (size_t)(srow) * KD1 + cg;
    const size_t boff1 = (size_t)(128 + srow) * KD1 + cg;

    floatx4 acc[2][4];
#pragma unroll
    for (int a = 0; a < 2; a++)
#pragma unroll
        for (int b = 0; b < 4; b++)
            acc[a][b] = floatx4{0.f, 0.f, 0.f, 0.f};

    const int rsw = (l16 >> 1) & 3;

#define STAGE(buf, ck) do {                                                         \
        if (tid < 256)                                                              \
        __builtin_amdgcn_global_load_lds((gas_t)(const void*)(A + aoff + (ck)*32),  \
            (las_t)(void*)(smem + (buf)*2048 + wave*512), 16, 0, 0);                \
        __builtin_amdgcn_global_load_lds((gas_t)(const void*)(Bw + boff0 + (ck)*32),\
            (las_t)(void*)(smem + 4096 + (buf)*8192 + wave*512), 16, 0, 0);         \
        __builtin_amdgcn_global_load_lds((gas_t)(const void*)(Bw + boff1 + (ck)*32),\
            (las_t)(void*)(smem + 4096 + (buf)*8192 + 4096 + wave*512), 16, 0, 0);  \
    } while (0)

    STAGE(0, 0);
    __syncthreads();
    for (int ck = 0; ck < 12; ck++) {
        const int cur = ck & 1;
        if (ck + 1 < 12) STAGE(cur ^ 1, ck + 1);
        const short* Ab = smem + cur * 2048;
        const short* Bb = smem + 4096 + cur * 8192;
        short8 af[2], bfr[4];
#pragma unroll
        for (int mb = 0; mb < 2; mb++)
            af[mb] = *(const short8*)(Ab + (wm * 32 + mb * 16 + l16) * 32 + ((quad ^ rsw) * 8));
#pragma unroll
        for (int nb = 0; nb < 4; nb++)
            bfr[nb] = *(const short8*)(Bb + (wn * 64 + nb * 16 + l16) * 32 + ((quad ^ rsw) * 8));
#pragma unroll
        for (int mb = 0; mb < 2; mb++)
#pragma unroll
            for (int nb = 0; nb < 4; nb++)
                acc[mb][nb] = __builtin_amdgcn_mfma_f32_16x16x32_bf16(af[mb], bfr[nb], acc[mb][nb], 0, 0, 0);
        __syncthreads();
    }
#undef STAGE

    gemm_epilogue64(smem, acc, bias, Out, Ss, Sq, m0, tid, wm, wn, quad, l16);
}

// ---------------- gemm2: y2 = relu(BN1(y1)) @ W2b^T + b2 ---------------------
// R15: SC1/SH1 computed in-block (256 threads) from the BN1 accumulators --
// valid because gemm1 completed at the kernel boundary. Stats -> atomics.
__global__ __launch_bounds__(512, 6) void gemm_bn2(
    const unsigned short* __restrict__ Y1in,
    const unsigned short* __restrict__ W2b,
    const float* __restrict__ S1s, const float* __restrict__ S1q,
    const float* __restrict__ g1, const float* __restrict__ be1,
    const float* __restrict__ b2,
    unsigned short* __restrict__ Y2out,
    float* __restrict__ Ss, float* __restrict__ Sq)
{
    __shared__ short smem[20480];   // 40 KB: As[2] @ 0/2048, Bs[2] @ 4096/12288
    __shared__ __align__(16) float sc1l[256], sh1l[256];
    const int tid  = threadIdx.x;
    const int wave = tid >> 6, lane = tid & 63;
    const int wm   = wave & 1, wn = wave >> 1;
    const int quad = lane >> 4, l16 = lane & 15;
    const long m0 = (long)blockIdx.x * 64;

    if (tid < 256)
        bn_scale_shift(S1s[tid], S1q[tid], g1[tid], be1[tid], sc1l[tid], sh1l[tid]);

    const int srow = tid >> 2;                              // 0..127
    const int cg   = ((tid & 3) ^ ((tid >> 3) & 3)) * 8;    // source col-chunk base
    const unsigned short* Ap = Y1in + (size_t)(m0 + (srow & 63)) * 256 + cg;
    const size_t boff0 = (size_t)(srow) * 256 + cg;
    const size_t boff1 = (size_t)(128 + srow) * 256 + cg;

    floatx4 acc[2][4];
#pragma unroll
    for (int a = 0; a < 2; a++)
#pragma unroll
        for (int b = 0; b < 4; b++)
            acc[a][b] = floatx4{0.f, 0.f, 0.f, 0.f};

    const int rsw = (l16 >> 1) & 3;

#define STAGE_B(buf, ck) do {                                                        \
        __builtin_amdgcn_global_load_lds((gas_t)(const void*)(W2b + boff0 + (ck)*32),\
            (las_t)(void*)(smem + 4096 + (buf)*8192 + wave*512), 16, 0, 0);          \
        __builtin_amdgcn_global_load_lds((gas_t)(const void*)(W2b + boff1 + (ck)*32),\
            (las_t)(void*)(smem + 4096 + (buf)*8192 + 4096 + wave*512), 16, 0, 0);   \
    } while (0)

    // transform-write of A chunk ck into buffer buf (tid<256 only; regs preloaded)
#define XSTORE(buf, ck, r0, r1) do {                                            \
        const int c0 = (ck) * 32 + cg;                                          \
        float4 s0 = *(const float4*)(sc1l + c0), s1 = *(const float4*)(sc1l + c0 + 4); \
        float4 h0 = *(const float4*)(sh1l + c0), h1 = *(const float4*)(sh1l + c0 + 4); \
        short8 o;                                                               \
        o[0] = (short)f2b(fmaxf(fmaf(b2f(r0.x), s0.x, h0.x), 0.f));             \
        o[1] = (short)f2b(fmaxf(fmaf(b2f(r0.y), s0.y, h0.y), 0.f));             \
        o[2] = (short)f2b(fmaxf(fmaf(b2f(r0.z), s0.z, h0.z), 0.f));             \
        o[3] = (short)f2b(fmaxf(fmaf(b2f(r0.w), s0.w, h0.w), 0.f));             \
        o[4] = (short)f2b(fmaxf(fmaf(b2f(r1.x), s1.x, h1.x), 0.f));             \
        o[5] = (short)f2b(fmaxf(fmaf(b2f(r1.y), s1.y, h1.y), 0.f));             \
        o[6] = (short)f2b(fmaxf(fmaf(b2f(r1.z), s1.z, h1.z), 0.f));             \
        o[7] = (short)f2b(fmaxf(fmaf(b2f(r1.w), s1.w, h1.w), 0.f));             \
        *(short8*)(smem + (buf) * 2048 + tid * 8) = o;                          \
    } while (0)

    STAGE_B(0, 0);
    __syncthreads();              // sc1l/sh1l ready for all; LDS staged
    if (tid < 256) {
        ushort4 r0 = *(const ushort4*)(Ap);
        ushort4 r1 = *(const ushort4*)(Ap + 4);
        XSTORE(0, 0, r0, r1);
    }
    __syncthreads();
    for (int ck = 0; ck < 8; ck++) {
        const int cur = ck & 1;
        ushort4 r0 = {}, r1 = {};
        if (tid < 256 && ck + 1 < 8) {          // issue next-A loads early
            r0 = *(const ushort4*)(Ap + (ck + 1) * 32);
            r1 = *(const ushort4*)(Ap + (ck + 1) * 32 + 4);
        }
        if (ck + 1 < 8) STAGE_B(cur ^ 1, ck + 1);
        const short* Ab = smem + cur * 2048;
        const short* Bb = smem + 4096 + cur * 8192;
        short8 af[2], bfr[4];
#pragma unroll
        for (int mb = 0; mb < 2; mb++)
            af[mb] = *(const short8*)(Ab + (wm * 32 + mb * 16 + l16) * 32 + ((quad ^ rsw) * 8));
#pragma unroll
        for (int nb = 0; nb < 4; nb++)
            bfr[nb] = *(const short8*)(Bb + (wn * 64 + nb * 16 + l16) * 32 + ((quad ^ rsw) * 8));
#pragma unroll
        for (int mb = 0; mb < 2; mb++)
#pragma unroll
            for (int nb = 0; nb < 4; nb++)
                acc[mb][nb] = __builtin_amdgcn_mfma_f32_16x16x32_bf16(af[mb], bfr[nb], acc[mb][nb], 0, 0, 0);
        if (tid < 256 && ck + 1 < 8) XSTORE(cur ^ 1, ck + 1, r0, r1);  // after MFMAs
        __syncthreads();
    }
#undef XSTORE
#undef STAGE_B

    gemm_epilogue64(smem, acc, b2, Y2out, Ss, Sq, m0, tid, wm, wn, quad, l16);
}

// ---------------- final BN apply + relu: y2 bf16 -> d_out fp32 ----------------
// R15: SC2/SH2 computed per block (256 threads, 1 col each) from the BN2
// accumulators -- valid because gemm2 completed at the kernel boundary.
__global__ __launch_bounds__(256) void final_apply(
    const unsigned short* __restrict__ y2,
    const float* __restrict__ S2s, const float* __restrict__ S2q,
    const float* __restrict__ g2, const float* __restrict__ be2,
    float* __restrict__ out)
{
    __shared__ __align__(16) float sc[256], sh[256];
    const int tid = threadIdx.x;
    bn_scale_shift(S2s[tid], S2q[tid], g2[tid], be2[tid], sc[tid], sh[tid]);
    __syncthreads();

    size_t t = (size_t)blockIdx.x * 256 + tid;   // 2,097,152 threads x 8 elems
    int c = ((int)t & 31) * 8;
    const ushort4* in = (const ushort4*)y2 + t * 2;
    ushort4 a = in[0], b = in[1];
    float4 s0 = *(const float4*)(sc + c), s1 = *(const float4*)(sc + c + 4);
    float4 h0 = *(const float4*)(sh + c), h1 = *(const float4*)(sh + c + 4);
    float4 o0, o1;
    o0.x = fmaxf(fmaf(b2f(a.x), s0.x, h0.x), 0.f);
    o0.y = fmaxf(fmaf(b2f(a.y), s0.y, h0.y), 0.f);
    o0.z = fmaxf(fmaf(b2f(a.z), s0.z, h0.z), 0.f);
    o0.w = fmaxf(fmaf(b2f(a.w), s0.w, h0.w), 0.f);
    o1.x = fmaxf(fmaf(b2f(b.x), s1.x, h1.x), 0.f);
    o1.y = fmaxf(fmaf(b2f(b.y), s1.y, h1.y), 0.f);
    o1.z = fmaxf(fmaf(b2f(b.z), s1.z, h1.z), 0.f);
    o1.w = fmaxf(fmaf(b2f(b.w), s1.w, h1.w), 0.f);
    ((float4*)out)[t * 2]     = o0;
    ((float4*)out)[t * 2 + 1] = o1;
}

extern "C" void kernel_launch(void* const* d_in, const int* in_sizes, int n_in,
                              void* d_out, int out_size, void* d_ws, size_t ws_size,
                              hipStream_t stream) {
    (void)in_sizes; (void)n_in; (void)out_size; (void)ws_size;
    const float* xyz1 = (const float*)d_in[0];
    const float* xyz2 = (const float*)d_in[1];
    const float* f1   = (const float*)d_in[2];
    const float* f2   = (const float*)d_in[3];
    const float* W1   = (const float*)d_in[4];
    const float* b1   = (const float*)d_in[5];
    const float* g1   = (const float*)d_in[6];
    const float* be1  = (const float*)d_in[7];
    const float* W2   = (const float*)d_in[8];
    const float* b2   = (const float*)d_in[9];
    const float* g2   = (const float*)d_in[10];
    const float* be2  = (const float*)d_in[11];

    char* ws = (char*)d_ws;
    unsigned short* X    = (unsigned short*)(ws + X_OFF);
    unsigned short* Y1   = (unsigned short*)(ws + Y1_OFF);    // y1, reused as y2
    unsigned short* W1b  = (unsigned short*)(ws + W1B_OFF);
    unsigned short* W2b  = (unsigned short*)(ws + W2B_OFF);
    float*          PS1s = (float*)(ws + PS_OFF);
    float*          PS1q = (float*)(ws + PS_OFF + 1024);
    float*          PS2s = (float*)(ws + PS_OFF + 2048);
    float*          PS2q = (float*)(ws + PS_OFF + 3072);

    knn_interp_kernel<<<1344, 512, 0, stream>>>(xyz1, xyz2, f1, f2, W1, W2, W1b, W2b, X, PS1s);
    gemm_bn1<<<1024, 512, 0, stream>>>(X, W1b, b1, Y1, PS1s, PS1q);
    gemm_bn2<<<1024, 512, 0, stream>>>(Y1, W2b, PS1s, PS1q, g1, be1, b2, Y1, PS2s, PS2q);
    final_apply<<<(NQ * DH) / (8 * 256), 256, 0, stream>>>(Y1, PS2s, PS2q, g2, be2, (float*)d_out);
}

// Round 10
// 217.226 us; speedup vs baseline: 3.2397x; 1.1710x over previous
//
#include <hip/hip_runtime.h>
#include <hip/hip_bf16.h>

// Problem constants (fixed by setup_inputs)
#define B_    16
#define N1    1024
#define NP    4096
#define D1c   256
#define D2c   128
#define DH    256
#define NQ    (B_*NP)        // 65536 rows
#define KD1   (D1c+D2c)      // 384

// Workspace layout (bytes).
#define X_OFF      0ul                     // x bf16: 65536*384*2
#define Y1_OFF     50331648ul              // y1 / y2 bf16: 65536*256*2
#define W1B_OFF    85467136ul              // bf16 W1: 256*384*2
#define W2B_OFF    85663744ul              // bf16 W2: 256*256*2
#define PS_OFF     85794816ul              // BN accumulators: 4 x [8][256] floats
// PS1s @ +0, PS1q @ +8192, PS2s @ +16384, PS2q @ +24576 (bytes); 32 KB total

using short8  = __attribute__((ext_vector_type(8))) short;
using floatx4 = __attribute__((ext_vector_type(4))) float;
using f4v     = __attribute__((ext_vector_type(4))) float;
using f2v     = __attribute__((ext_vector_type(2))) float;
typedef const __attribute__((address_space(1))) unsigned int* gas_t;
typedef __attribute__((address_space(3))) unsigned int* las_t;
typedef const __attribute__((address_space(4))) float* c4f_t;   // constant AS -> s_load
typedef const __attribute__((address_space(4))) f4v*   c4v_t;

// bf16 RNE cast (bit-level, matches np/jax round-to-nearest-even; inputs finite)
static __device__ __forceinline__ unsigned short f2b(float f) {
    unsigned int u = __builtin_bit_cast(unsigned int, f);
    return (unsigned short)((u + 0x7FFFu + ((u >> 16) & 1u)) >> 16);
}
static __device__ __forceinline__ float b2f(unsigned short u) {
    unsigned int x = ((unsigned int)u) << 16;
    return __builtin_bit_cast(float, x);
}

// ---------------- fused kNN + interp/concat (+ weight cvt on spare blocks) ----
// R11-proven body. wcvt blocks 1024..1039 additionally zero the 32 KB BN
// accumulator region (stream-ordered before gemm1 -> re-initialized every
// iteration, replay/poison safe; R13/R15-proven pattern).
__global__ __launch_bounds__(512, 8) void knn_interp_kernel(
    const float* __restrict__ xyz1, const float* __restrict__ xyz2,
    const float* __restrict__ f1,   const float* __restrict__ feat2,
    const float* __restrict__ W1,   const float* __restrict__ W2,
    unsigned short* __restrict__ W1b, unsigned short* __restrict__ W2b,
    unsigned short* __restrict__ x,  float* __restrict__ bnz)
{
#pragma clang fp contract(off)
    const int tid = threadIdx.x;
    if (blockIdx.x >= 1024) {            // ---- weight conversion blocks ----
        if (blockIdx.x < 1040) bnz[(blockIdx.x - 1024) * 512 + tid] = 0.f;  // 8192 floats
        int i = (blockIdx.x - 1024) * 512 + tid;     // 320 blocks x 512 = 163840
        if (i < DH * KD1) W1b[i] = f2b(W1[i]);
        else              W2b[i - DH * KD1] = f2b(W2[i - DH * KD1]);
        return;
    }

    __shared__ float pd[24 * 64];
    __shared__ int   pi[24 * 64];
    __shared__ int   sidx[64 * 3];
    __shared__ float swt [64 * 3];

    const int xcd  = blockIdx.x & 7;
    const int slot = blockIdx.x >> 3;          // 0..127
    const int batch = xcd * 2 + (slot >> 6);
    const int qblk  = slot & 63;

    const int ql  = tid & 63;
    const int seg = tid >> 6;                  // 0..7, wave index (uniform)
    const int seg_u = __builtin_amdgcn_readfirstlane(seg);
    const int n = batch * NP + qblk * 64 + ql;
    const float* qp = xyz2 + (size_t)n * 3;
    const float qx = qp[0], qy = qp[1], qz = qp[2];
    const f2v qx2 = {qx, qx}, qy2 = {qy, qy}, qz2 = {qz, qz};

    c4f_t cp = (c4f_t)(const void*)(xyz1 + (size_t)batch * (N1 * 3))
               + (size_t)seg_u * 384;          // 128 candidates * 3 floats

    float d0 = 3.4e38f, d1v = 3.4e38f, d2v = 3.4e38f;
    int   i0 = 0, i1 = 0, i2 = 0;

#define SEL(jj, dd) do {                                                      \
        bool c0 = (dd) < d0, c1 = (dd) < d1v, c2 = (dd) < d2v;                \
        i2 = c2 ? (c1 ? i1 : (jj)) : i2;                                      \
        i1 = c1 ? (c0 ? i0 : (jj)) : i1;                                      \
        i0 = c0 ? (jj) : i0;                                                  \
        d2v = __builtin_amdgcn_fmed3f(d1v, d2v, (dd));                        \
        d1v = __builtin_amdgcn_fmed3f(d0, d1v, (dd));                         \
        d0  = fminf(d0, (dd));                                                \
    } while (0)

    const int jbase = seg_u * 128;
    // explicit next-iteration prefetch rotation of the candidate triple
    f4v p0 = *(c4v_t)(cp);
    f4v p1 = *(c4v_t)(cp + 4);
    f4v p2 = *(c4v_t)(cp + 8);
    for (int j = 0; j < 128; j += 4) {
        f4v q0 = p0, q1 = p1, q2 = p2;
        if (j + 4 < 128) {
            p0 = *(c4v_t)(cp + (j + 4) * 3);
            p1 = *(c4v_t)(cp + (j + 4) * 3 + 4);
            p2 = *(c4v_t)(cp + (j + 4) * 3 + 8);
        }
        {
            f2v cx2 = {q0.x, q0.w}, cy2 = {q0.y, q1.x}, cz2 = {q0.z, q1.y};
            f2v dx2 = qx2 - cx2, dy2 = qy2 - cy2, dz2 = qz2 - cz2;
            f2v dd2 = (dx2 * dx2 + dy2 * dy2) + dz2 * dz2;
            SEL(jbase + j + 0, dd2.x);
            SEL(jbase + j + 1, dd2.y);
        }
        {
            f2v cx2 = {q1.z, q2.y}, cy2 = {q1.w, q2.z}, cz2 = {q2.x, q2.w};
            f2v dx2 = qx2 - cx2, dy2 = qy2 - cy2, dz2 = qz2 - cz2;
            f2v dd2 = (dx2 * dx2 + dy2 * dy2) + dz2 * dz2;
            SEL(jbase + j + 2, dd2.x);
            SEL(jbase + j + 3, dd2.y);
        }
    }
#undef SEL

    pd[(seg * 3 + 0) * 64 + ql] = d0;   pi[(seg * 3 + 0) * 64 + ql] = i0;
    pd[(seg * 3 + 1) * 64 + ql] = d1v;  pi[(seg * 3 + 1) * 64 + ql] = i1;
    pd[(seg * 3 + 2) * 64 + ql] = d2v;  pi[(seg * 3 + 2) * 64 + ql] = i2;
    __syncthreads();

    if (tid < 64) {
        float e0 = pd[0 * 64 + tid], e1 = pd[1 * 64 + tid], e2 = pd[2 * 64 + tid];
        int   j0 = pi[0 * 64 + tid], j1 = pi[1 * 64 + tid], j2 = pi[2 * 64 + tid];
#pragma unroll
        for (int s = 3; s < 24; s++) {
            float d = pd[s * 64 + tid];
            int   i = pi[s * 64 + tid];
            bool c2 = d < e2;
            e2 = c2 ? d : e2;  j2 = c2 ? i : j2;
            bool c1 = e2 < e1;
            float tf = e1; e1 = c1 ? e2 : e1; e2 = c1 ? tf : e2;
            int   ti = j1; j1 = c1 ? j2 : j1; j2 = c1 ? ti : j2;
            bool c0 = e1 < e0;
            tf = e0; e0 = c0 ? e1 : e0; e1 = c0 ? tf : e1;
            ti = j0; j0 = c0 ? j1 : j0; j1 = c0 ? ti : j1;
        }
        const float eps = 1.1920929e-07f;
        float v0 = 1.0f / __fadd_rn(e0, eps);
        float v1 = 1.0f / __fadd_rn(e1, eps);
        float v2 = 1.0f / __fadd_rn(e2, eps);
        float s  = __fadd_rn(__fadd_rn(v0, v1), v2);
        sidx[tid * 3 + 0] = j0;  swt[tid * 3 + 0] = v0 / s;
        sidx[tid * 3 + 1] = j1;  swt[tid * 3 + 1] = v1 / s;
        sidx[tid * 3 + 2] = j2;  swt[tid * 3 + 2] = v2 / s;
    }
    __syncthreads();

    const int lane = tid & 63, wv = tid >> 6;
    const float* fb = f1 + (size_t)batch * (N1 * D1c);
#pragma unroll 4
    for (int it = 0; it < 8; it++) {
        const int q  = wv * 8 + it;
        const int nr = batch * NP + qblk * 64 + q;
        const int a0 = sidx[q * 3 + 0], a1 = sidx[q * 3 + 1], a2 = sidx[q * 3 + 2];
        const float w0 = swt[q * 3 + 0], w1 = swt[q * 3 + 1], w2 = swt[q * 3 + 2];
        float4 a = *(const float4*)(fb + (size_t)a0 * D1c + lane * 4);
        float4 b = *(const float4*)(fb + (size_t)a1 * D1c + lane * 4);
        float4 c = *(const float4*)(fb + (size_t)a2 * D1c + lane * 4);
        ushort4 o;
        o.x = f2b(__fadd_rn(__fadd_rn(__fmul_rn(a.x,w0), __fmul_rn(b.x,w1)), __fmul_rn(c.x,w2)));
        o.y = f2b(__fadd_rn(__fadd_rn(__fmul_rn(a.y,w0), __fmul_rn(b.y,w1)), __fmul_rn(c.y,w2)));
        o.z = f2b(__fadd_rn(__fadd_rn(__fmul_rn(a.z,w0), __fmul_rn(b.z,w1)), __fmul_rn(c.z,w2)));
        o.w = f2b(__fadd_rn(__fadd_rn(__fmul_rn(a.w,w0), __fmul_rn(b.w,w1)), __fmul_rn(c.w,w2)));
        *(ushort4*)(x + (size_t)nr * KD1 + lane * 4) = o;
        float2 f = *(const float2*)(feat2 + (size_t)nr * D2c + lane * 2);
        ushort2 o2; o2.x = f2b(f.x); o2.y = f2b(f.y);
        *(ushort2*)(x + (size_t)nr * KD1 + D1c + lane * 2) = o2;
    }
}

// ---------------- shared gemm epilogue, BM=64 (R8-proven) --------------------
// R16: per-tile column sums (bit-identical to R11) atomicAdd into the block's
// 8-way-sharded slot (contention/address = 128, vs R15's 1024 -> negligible).
static __device__ __forceinline__ void gemm_epilogue64(
    short* smem, floatx4 (&acc)[2][4], const float* __restrict__ bias,
    unsigned short* __restrict__ Out, float* __restrict__ Ss, float* __restrict__ Sq,
    long m0, int tid, int wm, int wn, int quad, int l16)
{
    float sv[4], qv[4];
#pragma unroll
    for (int nb = 0; nb < 4; nb++) {
        const int col = wn * 64 + nb * 16 + l16;
        const float bia = bias[col];
        float s = 0.f, q = 0.f;
#pragma unroll
        for (int mb = 0; mb < 2; mb++)
#pragma unroll
            for (int r = 0; r < 4; r++) {
                float v = acc[mb][nb][r] + bia;
                acc[mb][nb][r] = v;
                s += v; q += v * v;
            }
        s += __shfl_xor(s, 16); s += __shfl_xor(s, 32);
        q += __shfl_xor(q, 16); q += __shfl_xor(q, 32);
        sv[nb] = s; qv[nb] = q;
    }
    // combine wm halves via LDS floats (first 4 KB of smem; K-loop done)
    float* fs = (float*)smem;          // 512 floats: [wm][col]
    float* fq = (float*)smem + 512;    // 512 floats
    if (quad == 0) {
#pragma unroll
        for (int nb = 0; nb < 4; nb++) {
            const int col = wn * 64 + nb * 16 + l16;
            fs[wm * 256 + col] = sv[nb];
            fq[wm * 256 + col] = qv[nb];
        }
    }
    __syncthreads();
    if (wm == 0 && quad == 0) {
#pragma unroll
        for (int nb = 0; nb < 4; nb++) {
            const int col = wn * 64 + nb * 16 + l16;
            atomicAdd(&Ss[col], fs[col] + fs[256 + col]);
            atomicAdd(&Sq[col], fq[col] + fq[256 + col]);
        }
    }
    __syncthreads();   // fs/fq reads done before transpose overwrites region

#pragma unroll
    for (int mb = 0; mb < 2; mb++)
#pragma unroll
        for (int r = 0; r < 4; r++) {
            const int rl = wm * 32 + mb * 16 + quad * 4 + r;
#pragma unroll
            for (int nb = 0; nb < 4; nb++) {
                const int col = wn * 64 + nb * 16 + l16;
                smem[rl * 256 + ((((col >> 3) + rl) & 31) << 3) + (col & 7)] =
                    (short)f2b(acc[mb][nb][r]);
            }
        }
    __syncthreads();
#pragma unroll
    for (int rr = 0; rr < 4; rr++) {
        const int rl = rr * 16 + (tid >> 5);
        const int c  = tid & 31;
        short8 v = *(const short8*)(smem + rl * 256 + (((c + rl) & 31) << 3));
        *(short8*)(Out + (size_t)(m0 + rl) * 256 + c * 8) = v;
    }
}

// BN scale/shift from accumulated sums (exact finalize_bn arithmetic)
static __device__ __forceinline__ void bn_scale_shift(
    float s, float q, float gg, float bb, float& sc, float& sh)
{
    float m  = s * (1.0f / (float)NQ);
    float v  = q * (1.0f / (float)NQ) - m * m;
    float rs = rsqrtf(v + 1e-5f);
    float a  = rs * gg;
    sc = a;
    sh = fmaf(-m, a, bb);
}

// ---------------- gemm1: y1 = X @ W1b^T + b1, stats -> sharded atomics -------
__global__ __launch_bounds__(512, 6) void gemm_bn1(
    const unsigned short* __restrict__ A,
    const unsigned short* __restrict__ Bw,
    const float* __restrict__ bias,
    unsigned short* __restrict__ Out,
    float* __restrict__ S1s, float* __restrict__ S1q)
{
    __shared__ short smem[20480];   // 40 KB: As[2] @ 0/2048, Bs[2] @ 4096/12288
    const int tid  = threadIdx.x;
    const int wave = tid >> 6, lane = tid & 63;
    const int wm   = wave & 1, wn = wave >> 1;
    const int quad = lane >> 4, l16 = lane & 15;
    const long m0 = (long)blockIdx.x * 64;
    const int slot = blockIdx.x & 7;

    const int srow = tid >> 2;                              // 0..127
    const int cg   = ((tid & 3) ^ ((tid >> 3) & 3)) * 8;
    const size_t aoff  = (size_t)(m0 + (srow & 63)) * KD1 + cg;  // used by tid<256
    const size_t boff0 = (size_t)(srow) * KD1 + cg;
    const size_t boff1 = (size_t)(128 + srow) * KD1 + cg;

    floatx4 acc[2][4];
#pragma unroll
    for (int a = 0; a < 2; a++)
#pragma unroll
        for (int b = 0; b < 4; b++)
            acc[a][b] = floatx4{0.f, 0.f, 0.f, 0.f};

    const int rsw = (l16 >> 1) & 3;

#define STAGE(buf, ck) do {                                                         \
        if (tid < 256)                                                              \
        __builtin_amdgcn_global_load_lds((gas_t)(const void*)(A + aoff + (ck)*32),  \
            (las_t)(void*)(smem + (buf)*2048 + wave*512), 16, 0, 0);                \
        __builtin_amdgcn_global_load_lds((gas_t)(const void*)(Bw + boff0 + (ck)*32),\
            (las_t)(void*)(smem + 4096 + (buf)*8192 + wave*512), 16, 0, 0);         \
        __builtin_amdgcn_global_load_lds((gas_t)(const void*)(Bw + boff1 + (ck)*32),\
            (las_t)(void*)(smem + 4096 + (buf)*8192 + 4096 + wave*512), 16, 0, 0);  \
    } while (0)

    STAGE(0, 0);
    __syncthreads();
    for (int ck = 0; ck < 12; ck++) {
        const int cur = ck & 1;
        if (ck + 1 < 12) STAGE(cur ^ 1, ck + 1);
        const short* Ab = smem + cur * 2048;
        const short* Bb = smem + 4096 + cur * 8192;
        short8 af[2], bfr[4];
#pragma unroll
        for (int mb = 0; mb < 2; mb++)
            af[mb] = *(const short8*)(Ab + (wm * 32 + mb * 16 + l16) * 32 + ((quad ^ rsw) * 8));
#pragma unroll
        for (int nb = 0; nb < 4; nb++)
            bfr[nb] = *(const short8*)(Bb + (wn * 64 + nb * 16 + l16) * 32 + ((quad ^ rsw) * 8));
#pragma unroll
        for (int mb = 0; mb < 2; mb++)
#pragma unroll
            for (int nb = 0; nb < 4; nb++)
                acc[mb][nb] = __builtin_amdgcn_mfma_f32_16x16x32_bf16(af[mb], bfr[nb], acc[mb][nb], 0, 0, 0);
        __syncthreads();
    }
#undef STAGE

    gemm_epilogue64(smem, acc, bias, Out, S1s + slot * 256, S1q + slot * 256,
                    m0, tid, wm, wn, quad, l16);
}

// ---------------- gemm2: y2 = relu(BN1(y1)) @ W2b^T + b2 ---------------------
// SC1/SH1 computed in-block from the 8-slot BN1 accumulators (valid: gemm1
// completed at the kernel boundary). Stats -> sharded atomics.
__global__ __launch_bounds__(512, 6) void gemm_bn2(
    const unsigned short* __restrict__ Y1in,
    const unsigned short* __restrict__ W2b,
    const float* __restrict__ S1s, const float* __restrict__ S1q,
    const float* __restrict__ g1, const float* __restrict__ be1,
    const float* __restrict__ b2,
    unsigned short* __restrict__ Y2out,
    float* __restrict__ S2s, float* __restrict__ S2q)
{
    __shared__ short smem[20480];   // 40 KB: As[2] @ 0/2048, Bs[2] @ 4096/12288
    __shared__ __align__(16) float sc1l[256], sh1l[256];
    const int tid  = threadIdx.x;
    const int wave = tid >> 6, lane = tid & 63;
    const int wm   = wave & 1, wn = wave >> 1;
    const int quad = lane >> 4, l16 = lane & 15;
    const long m0 = (long)blockIdx.x * 64;
    const int slot = blockIdx.x & 7;

    if (tid < 256) {
        float s = 0.f, q = 0.f;
#pragma unroll
        for (int k = 0; k < 8; k++) {
            s += S1s[k * 256 + tid];
            q += S1q[k * 256 + tid];
        }
        bn_scale_shift(s, q, g1[tid], be1[tid], sc1l[tid], sh1l[tid]);
    }

    const int srow = tid >> 2;                              // 0..127
    const int cg   = ((tid & 3) ^ ((tid >> 3) & 3)) * 8;    // source col-chunk base
    const unsigned short* Ap = Y1in + (size_t)(m0 + (srow & 63)) * 256 + cg;
    const size_t boff0 = (size_t)(srow) * 256 + cg;
    const size_t boff1 = (size_t)(128 + srow) * 256 + cg;

    floatx4 acc[2][4];
#pragma unroll
    for (int a = 0; a < 2; a++)
#pragma unroll
        for (int b = 0; b < 4; b++)
            acc[a][b] = floatx4{0.f, 0.f, 0.f, 0.f};

    const int rsw = (l16 >> 1) & 3;

#define STAGE_B(buf, ck) do {                                                        \
        __builtin_amdgcn_global_load_lds((gas_t)(const void*)(W2b + boff0 + (ck)*32),\
            (las_t)(void*)(smem + 4096 + (buf)*8192 + wave*512), 16, 0, 0);          \
        __builtin_amdgcn_global_load_lds((gas_t)(const void*)(W2b + boff1 + (ck)*32),\
            (las_t)(void*)(smem + 4096 + (buf)*8192 + 4096 + wave*512), 16, 0, 0);   \
    } while (0)

    // transform-write of A chunk ck into buffer buf (tid<256 only; regs preloaded)
#define XSTORE(buf, ck, r0, r1) do {                                            \
        const int c0 = (ck) * 32 + cg;                                          \
        float4 s0 = *(const float4*)(sc1l + c0), s1 = *(const float4*)(sc1l + c0 + 4); \
        float4 h0 = *(const float4*)(sh1l + c0), h1 = *(const float4*)(sh1l + c0 + 4); \
        short8 o;                                                               \
        o[0] = (short)f2b(fmaxf(fmaf(b2f(r0.x), s0.x, h0.x), 0.f));             \
        o[1] = (short)f2b(fmaxf(fmaf(b2f(r0.y), s0.y, h0.y), 0.f));             \
        o[2] = (short)f2b(fmaxf(fmaf(b2f(r0.z), s0.z, h0.z), 0.f));             \
        o[3] = (short)f2b(fmaxf(fmaf(b2f(r0.w), s0.w, h0.w), 0.f));             \
        o[4] = (short)f2b(fmaxf(fmaf(b2f(r1.x), s1.x, h1.x), 0.f));             \
        o[5] = (short)f2b(fmaxf(fmaf(b2f(r1.y), s1.y, h1.y), 0.f));             \
        o[6] = (short)f2b(fmaxf(fmaf(b2f(r1.z), s1.z, h1.z), 0.f));             \
        o[7] = (short)f2b(fmaxf(fmaf(b2f(r1.w), s1.w, h1.w), 0.f));             \
        *(short8*)(smem + (buf) * 2048 + tid * 8) = o;                          \
    } while (0)

    STAGE_B(0, 0);
    __syncthreads();              // sc1l/sh1l visible; B chunk 0 staged
    if (tid < 256) {
        ushort4 r0 = *(const ushort4*)(Ap);
        ushort4 r1 = *(const ushort4*)(Ap + 4);
        XSTORE(0, 0, r0, r1);
    }
    __syncthreads();
    for (int ck = 0; ck < 8; ck++) {
        const int cur = ck & 1;
        ushort4 r0 = {}, r1 = {};
        if (tid < 256 && ck + 1 < 8) {          // issue next-A loads early
            r0 = *(const ushort4*)(Ap + (ck + 1) * 32);
            r1 = *(const ushort4*)(Ap + (ck + 1) * 32 + 4);
        }
        if (ck + 1 < 8) STAGE_B(cur ^ 1, ck + 1);
        const short* Ab = smem + cur * 2048;
        const short* Bb = smem + 4096 + cur * 8192;
        short8 af[2], bfr[4];
#pragma unroll
        for (int mb = 0; mb < 2; mb++)
            af[mb] = *(const short8*)(Ab + (wm * 32 + mb * 16 + l16) * 32 + ((quad ^ rsw) * 8));
#pragma unroll
        for (int nb = 0; nb < 4; nb++)
            bfr[nb] = *(const short8*)(Bb + (wn * 64 + nb * 16 + l16) * 32 + ((quad ^ rsw) * 8));
#pragma unroll
        for (int mb = 0; mb < 2; mb++)
#pragma unroll
            for (int nb = 0; nb < 4; nb++)
                acc[mb][nb] = __builtin_amdgcn_mfma_f32_16x16x32_bf16(af[mb], bfr[nb], acc[mb][nb], 0, 0, 0);
        if (tid < 256 && ck + 1 < 8) XSTORE(cur ^ 1, ck + 1, r0, r1);  // after MFMAs
        __syncthreads();
    }
#undef XSTORE
#undef STAGE_B

    gemm_epilogue64(smem, acc, b2, Y2out, S2s + slot * 256, S2q + slot * 256,
                    m0, tid, wm, wn, quad, l16);
}

// ---------------- final BN apply + relu: y2 bf16 -> d_out fp32 ----------------
// SC2/SH2 computed per block (256 threads, 1 col each) from the 8-slot BN2
// accumulators (valid: gemm2 completed at the kernel boundary).
__global__ __launch_bounds__(256) void final_apply(
    const unsigned short* __restrict__ y2,
    const float* __restrict__ S2s, const float* __restrict__ S2q,
    const float* __restrict__ g2, const float* __restrict__ be2,
    float* __restrict__ out)
{
    __shared__ __align__(16) float sc[256], sh[256];
    const int tid = threadIdx.x;
    {
        float s = 0.f, q = 0.f;
#pragma unroll
        for (int k = 0; k < 8; k++) {
            s += S2s[k * 256 + tid];
            q += S2q[k * 256 + tid];
        }
        bn_scale_shift(s, q, g2[tid], be2[tid], sc[tid], sh[tid]);
    }
    __syncthreads();

    size_t t = (size_t)blockIdx.x * 256 + tid;   // 2,097,152 threads x 8 elems
    int c = ((int)t & 31) * 8;
    const ushort4* in = (const ushort4*)y2 + t * 2;
    ushort4 a = in[0], b = in[1];
    float4 s0 = *(const float4*)(sc + c), s1 = *(const float4*)(sc + c + 4);
    float4 h0 = *(const float4*)(sh + c), h1 = *(const float4*)(sh + c + 4);
    float4 o0, o1;
    o0.x = fmaxf(fmaf(b2f(a.x), s0.x, h0.x), 0.f);
    o0.y = fmaxf(fmaf(b2f(a.y), s0.y, h0.y), 0.f);
    o0.z = fmaxf(fmaf(b2f(a.z), s0.z, h0.z), 0.f);
    o0.w = fmaxf(fmaf(b2f(a.w), s0.w, h0.w), 0.f);
    o1.x = fmaxf(fmaf(b2f(b.x), s1.x, h1.x), 0.f);
    o1.y = fmaxf(fmaf(b2f(b.y), s1.y, h1.y), 0.f);
    o1.z = fmaxf(fmaf(b2f(b.z), s1.z, h1.z), 0.f);
    o1.w = fmaxf(fmaf(b2f(b.w), s1.w, h1.w), 0.f);
    ((float4*)out)[t * 2]     = o0;
    ((float4*)out)[t * 2 + 1] = o1;
}

extern "C" void kernel_launch(void* const* d_in, const int* in_sizes, int n_in,
                              void* d_out, int out_size, void* d_ws, size_t ws_size,
                              hipStream_t stream) {
    (void)in_sizes; (void)n_in; (void)out_size; (void)ws_size;
    const float* xyz1 = (const float*)d_in[0];
    const float* xyz2 = (const float*)d_in[1];
    const float* f1   = (const float*)d_in[2];
    const float* f2   = (const float*)d_in[3];
    const float* W1   = (const float*)d_in[4];
    const float* b1   = (const float*)d_in[5];
    const float* g1   = (const float*)d_in[6];
    const float* be1  = (const float*)d_in[7];
    const float* W2   = (const float*)d_in[8];
    const float* b2   = (const float*)d_in[9];
    const float* g2   = (const float*)d_in[10];
    const float* be2  = (const float*)d_in[11];

    char* ws = (char*)d_ws;
    unsigned short* X    = (unsigned short*)(ws + X_OFF);
    unsigned short* Y1   = (unsigned short*)(ws + Y1_OFF);    // y1, reused as y2
    unsigned short* W1b  = (unsigned short*)(ws + W1B_OFF);
    unsigned short* W2b  = (unsigned short*)(ws + W2B_OFF);
    float*          PS1s = (float*)(ws + PS_OFF);
    float*          PS1q = (float*)(ws + PS_OFF + 8192);
    float*          PS2s = (float*)(ws + PS_OFF + 16384);
    float*          PS2q = (float*)(ws + PS_OFF + 24576);

    knn_interp_kernel<<<1344, 512, 0, stream>>>(xyz1, xyz2, f1, f2, W1, W2, W1b, W2b, X, PS1s);
    gemm_bn1<<<1024, 512, 0, stream>>>(X, W1b, b1, Y1, PS1s, PS1q);
    gemm_bn2<<<1024, 512, 0, stream>>>(Y1, W2b, PS1s, PS1q, g1, be1, b2, Y1, PS2s, PS2q);
    final_apply<<<(NQ * DH) / (8 * 256), 256, 0, stream>>>(Y1, PS2s, PS2q, g2, be2, (float*)d_out);
}